// Round 4
// baseline (42.139 us; speedup 1.0000x reference)
//
#include <hip/hip_runtime.h>

#define NUM_SAMPLES 64
#define HIDDEN 64
#define Z_NEAR 2.0f
#define Z_FAR 6.0f

typedef _Float16 half8 __attribute__((ext_vector_type(8)));
typedef __fp16  fp16x2 __attribute__((ext_vector_type(2)));
typedef float   f32x2  __attribute__((ext_vector_type(2)));
typedef float   float4t __attribute__((ext_vector_type(4)));

// wave-per-ray, lane-per-sample; layer-1 affine-in-t factorization (fp32, pk_fma);
// layer-2 64->4 via mfma_f32_16x16x32_f16 (4 M-tiles x 2 K-tiles per ray).
__global__ __launch_bounds__(256) void render_kernel(
    const float* __restrict__ cam,    // 4x4
    const float* __restrict__ u,      // R x S
    const float* __restrict__ cdirs,  // R x 3
    const float* __restrict__ W1,     // 6 x 64
    const float* __restrict__ b1,     // 64
    const float* __restrict__ W2,     // 64 x 4
    const float* __restrict__ b2,     // 4
    float* __restrict__ out)          // R x 3
{
    const int lane = threadIdx.x & 63;
    const int wid  = threadIdx.x >> 6;
    const int ray  = blockIdx.x * 4 + wid;
    const int grp  = lane >> 4;       // 16-lane group (k-group / C row group)
    const int col  = lane & 15;       // A row (sample-in-tile) / B,C col

    __shared__ __align__(16) float Ash[4][HIDDEN];
    __shared__ __align__(16) float Bsh[4][HIDDEN];
    __shared__ float  tsh[4][NUM_SAMPLES];
    __shared__ float4 W2s[HIDDEN];
    __shared__ float  cst[4][NUM_SAMPLES * 5];     // stride 5: bank-conflict-free

    if (threadIdx.x < HIDDEN)
        W2s[threadIdx.x] = ((const float4*)W2)[threadIdx.x];

    // ray dir / origin
    const float cd0 = cdirs[ray*3+0], cd1 = cdirs[ray*3+1], cd2 = cdirs[ray*3+2];
    const float rd0 = fmaf(cam[0], cd0, fmaf(cam[1], cd1, cam[2]*cd2));
    const float rd1 = fmaf(cam[4], cd0, fmaf(cam[5], cd1, cam[6]*cd2));
    const float rd2 = fmaf(cam[8], cd0, fmaf(cam[9], cd1, cam[10]*cd2));
    const float o0 = cam[3], o1 = cam[7], o2 = cam[11];

    // per-hidden-unit affine coeffs: pre_h(t) = A_h*t + B_h ; lane computes h=lane
    {
        const int h = lane;
        const float w10 = W1[0*HIDDEN+h], w11 = W1[1*HIDDEN+h], w12 = W1[2*HIDDEN+h];
        const float w13 = W1[3*HIDDEN+h], w14 = W1[4*HIDDEN+h], w15 = W1[5*HIDDEN+h];
        const float A = fmaf(rd0, w10, fmaf(rd1, w11, rd2*w12));
        float B = fmaf(o0, w10, fmaf(o1, w11, o2*w12));
        B = fmaf(rd0, w13, fmaf(rd1, w14, fmaf(rd2, w15, B))) + b1[h];
        Ash[wid][lane] = A;
        Bsh[wid][lane] = B;
    }

    const float bin_dt = (Z_FAR - Z_NEAR) / (float)NUM_SAMPLES;
    const float uv = u[ray*NUM_SAMPLES + lane];             // coalesced
    const float t  = fmaf((float)lane + uv, bin_dt, Z_NEAR);
    tsh[wid][lane] = t;
    const float t_next = __shfl_down(t, 1);
    const float sep = (lane < NUM_SAMPLES-1) ? (t_next - t) : bin_dt;

    __syncthreads();

    // hoisted A/B coefficient pairs for this lane's k-slots: h = kt*32 + grp*8 + 2q
    f32x2 aA[2][4], aB[2][4];
    #pragma unroll
    for (int kt = 0; kt < 2; ++kt) {
        const int h0 = kt*32 + grp*8;
        const float4 a01 = *(const float4*)(&Ash[wid][h0]);
        const float4 a23 = *(const float4*)(&Ash[wid][h0+4]);
        const float4 b01 = *(const float4*)(&Bsh[wid][h0]);
        const float4 b23 = *(const float4*)(&Bsh[wid][h0+4]);
        aA[kt][0] = f32x2{a01.x, a01.y}; aA[kt][1] = f32x2{a01.z, a01.w};
        aA[kt][2] = f32x2{a23.x, a23.y}; aA[kt][3] = f32x2{a23.z, a23.w};
        aB[kt][0] = f32x2{b01.x, b01.y}; aB[kt][1] = f32x2{b01.z, b01.w};
        aB[kt][2] = f32x2{b23.x, b23.y}; aB[kt][3] = f32x2{b23.z, b23.w};
    }

    // B-fragment: B[k][col] = W2[h][col], zero for col>=4
    half8 bfrag[2];
    #pragma unroll
    for (int kt = 0; kt < 2; ++kt) {
        union { fp16x2 h2[4]; half8 h8; } bu;
        #pragma unroll
        for (int q = 0; q < 4; ++q) {
            const int h0 = kt*32 + grp*8 + q*2;
            float v0 = 0.0f, v1 = 0.0f;
            if (col < 4) {
                v0 = ((const float*)&W2s[h0  ])[col];
                v1 = ((const float*)&W2s[h0+1])[col];
            }
            bu.h2[q] = __builtin_amdgcn_cvt_pkrtz(v0, v1);
        }
        bfrag[kt] = bu.h8;
    }

    const fp16x2 hzero = {(__fp16)0.0f, (__fp16)0.0f};

    // 4 M-tiles of 16 samples; per tile: build A-frag (pk affine + pk relu) + 2 MFMA
    #pragma unroll
    for (int m = 0; m < 4; ++m) {
        const float tm = tsh[wid][col + 16*m];
        const f32x2 tv = {tm, tm};
        float4t c = {0.f, 0.f, 0.f, 0.f};
        #pragma unroll
        for (int kt = 0; kt < 2; ++kt) {
            union { fp16x2 h2[4]; half8 h8; } au;
            #pragma unroll
            for (int q = 0; q < 4; ++q) {
                const f32x2 pre = __builtin_elementwise_fma(aA[kt][q], tv, aB[kt][q]);
                const fp16x2 h = __builtin_amdgcn_cvt_pkrtz(pre.x, pre.y);
                au.h2[q] = __builtin_elementwise_max(h, hzero);
            }
            c = __builtin_amdgcn_mfma_f32_16x16x32_f16(au.h8, bfrag[kt], c, 0, 0, 0);
        }
        if (col < 4) {
            #pragma unroll
            for (int r = 0; r < 4; ++r) {
                const int sample = 16*m + grp*4 + r;
                cst[wid][sample*5 + col] = c[r];
            }
        }
    }

    __syncthreads();

    // read back this lane's sample outputs (stride 5: conflict-free)
    const float acc0 = cst[wid][lane*5 + 0] + b2[0];
    const float acc1 = cst[wid][lane*5 + 1] + b2[1];
    const float acc2 = cst[wid][lane*5 + 2] + b2[2];
    const float acc3 = cst[wid][lane*5 + 3] + b2[3];

    // volume rendering composite
    const float density = fmaxf(acc0, 0.0f);
    const float alpha = 1.0f - __expf(-density * sep);
    const float om = 1.0f - alpha;

    float P = om;
    #pragma unroll
    for (int off = 1; off < 64; off <<= 1) {
        const float v = __shfl_up(P, off);
        if (lane >= off) P *= v;
    }
    float T = __shfl_up(P, 1);
    if (lane == 0) T = 1.0f;
    const float w = alpha * T;

    float c0 = w * __builtin_amdgcn_rcpf(1.0f + __expf(-acc1));
    float c1 = w * __builtin_amdgcn_rcpf(1.0f + __expf(-acc2));
    float c2 = w * __builtin_amdgcn_rcpf(1.0f + __expf(-acc3));
    #pragma unroll
    for (int off = 32; off >= 1; off >>= 1) {
        c0 += __shfl_xor(c0, off);
        c1 += __shfl_xor(c1, off);
        c2 += __shfl_xor(c2, off);
    }
    if (lane == 0) {
        out[ray*3+0] = c0;
        out[ray*3+1] = c1;
        out[ray*3+2] = c2;
    }
}

extern "C" void kernel_launch(void* const* d_in, const int* in_sizes, int n_in,
                              void* d_out, int out_size, void* d_ws, size_t ws_size,
                              hipStream_t stream) {
    const float* cam   = (const float*)d_in[0];
    const float* u     = (const float*)d_in[1];
    const float* cdirs = (const float*)d_in[2];
    const float* W1    = (const float*)d_in[3];
    const float* b1    = (const float*)d_in[4];
    const float* W2    = (const float*)d_in[5];
    const float* b2    = (const float*)d_in[6];
    float* out = (float*)d_out;

    const int R = 256 * 256;
    dim3 grid(R / 4), block(256);
    render_kernel<<<grid, block, 0, stream>>>(cam, u, cdirs, W1, b1, W2, b2, out);
}

// Round 5
// 33.207 us; speedup vs baseline: 1.2690x; 1.2690x over previous
//
#include <hip/hip_runtime.h>

#define NUM_SAMPLES 64
#define HIDDEN 64
#define Z_NEAR 2.0f
#define Z_FAR 6.0f

typedef _Float16 half8 __attribute__((ext_vector_type(8)));
typedef __fp16  fp16x2 __attribute__((ext_vector_type(2)));
typedef float   f32x2  __attribute__((ext_vector_type(2)));
typedef float   float4t __attribute__((ext_vector_type(4)));

// 6-step wave64 inclusive add-scan, pure VALU (DPP), zero LDS traffic.
template<int CTRL, int RMASK>
__device__ __forceinline__ float dpp_add(float x) {
    const int m = __builtin_amdgcn_update_dpp(0, __float_as_int(x), CTRL, RMASK, 0xf, true);
    return x + __int_as_float(m);
}
__device__ __forceinline__ float wave_scan_add(float x) {
    x = dpp_add<0x111, 0xf>(x);   // row_shr:1
    x = dpp_add<0x112, 0xf>(x);   // row_shr:2
    x = dpp_add<0x114, 0xf>(x);   // row_shr:4
    x = dpp_add<0x118, 0xf>(x);   // row_shr:8
    x = dpp_add<0x142, 0xa>(x);   // row_bcast:15 -> rows 1,3
    x = dpp_add<0x143, 0xc>(x);   // row_bcast:31 -> rows 2,3
    return x;                     // lane63 = full sum
}

// wave-per-ray, lane-per-sample; layer-1 affine-in-t factorization (fp32);
// layer-2 64->4 via mfma_f32_16x16x32_f16; composite via DPP log-space scan.
// All LDS is per-wave ([wid]) -> no __syncthreads at all.
__global__ __launch_bounds__(256) void render_kernel(
    const float* __restrict__ cam,    // 4x4
    const float* __restrict__ u,      // R x S
    const float* __restrict__ cdirs,  // R x 3
    const float* __restrict__ W1,     // 6 x 64
    const float* __restrict__ b1,     // 64
    const float* __restrict__ W2,     // 64 x 4
    const float* __restrict__ b2,     // 4
    float* __restrict__ out)          // R x 3
{
    const int lane = threadIdx.x & 63;
    const int wid  = threadIdx.x >> 6;
    const int ray  = blockIdx.x * 4 + wid;
    const int grp  = lane >> 4;       // 16-lane group (k-group / C row group)
    const int col  = lane & 15;       // A row (sample-in-tile) / B,C col

    __shared__ __align__(16) float Ash[4][HIDDEN];
    __shared__ __align__(16) float Bsh[4][HIDDEN];
    __shared__ __align__(16) float tsh[4][NUM_SAMPLES];
    __shared__ __align__(16) __fp16 W2T[4][4][80];   // fp16 W2^T, padded rows
    __shared__ float cst[4][NUM_SAMPLES * 5];        // stride 5: conflict-free

    // per-wave fp16 W2^T staging (lane = hidden unit h)
    {
        const float4 w2row = ((const float4*)W2)[lane];
        W2T[wid][0][lane] = (__fp16)w2row.x;
        W2T[wid][1][lane] = (__fp16)w2row.y;
        W2T[wid][2][lane] = (__fp16)w2row.z;
        W2T[wid][3][lane] = (__fp16)w2row.w;
    }

    // ray dir / origin
    const float cd0 = cdirs[ray*3+0], cd1 = cdirs[ray*3+1], cd2 = cdirs[ray*3+2];
    const float rd0 = fmaf(cam[0], cd0, fmaf(cam[1], cd1, cam[2]*cd2));
    const float rd1 = fmaf(cam[4], cd0, fmaf(cam[5], cd1, cam[6]*cd2));
    const float rd2 = fmaf(cam[8], cd0, fmaf(cam[9], cd1, cam[10]*cd2));
    const float o0 = cam[3], o1 = cam[7], o2 = cam[11];

    // per-hidden-unit affine coeffs: pre_h(t) = A_h*t + B_h ; lane computes h=lane
    {
        const int h = lane;
        const float w10 = W1[0*HIDDEN+h], w11 = W1[1*HIDDEN+h], w12 = W1[2*HIDDEN+h];
        const float w13 = W1[3*HIDDEN+h], w14 = W1[4*HIDDEN+h], w15 = W1[5*HIDDEN+h];
        const float A = fmaf(rd0, w10, fmaf(rd1, w11, rd2*w12));
        float B = fmaf(o0, w10, fmaf(o1, w11, o2*w12));
        B = fmaf(rd0, w13, fmaf(rd1, w14, fmaf(rd2, w15, B))) + b1[h];
        Ash[wid][lane] = A;
        Bsh[wid][lane] = B;
    }

    const float bin_dt = (Z_FAR - Z_NEAR) / (float)NUM_SAMPLES;
    const float uv = u[ray*NUM_SAMPLES + lane];             // coalesced
    const float t  = fmaf((float)lane + uv, bin_dt, Z_NEAR);
    tsh[wid][lane] = t;

    // hoisted A/B coefficient pairs for this lane's k-slots: h = kt*32 + grp*8 + 2q
    f32x2 aA[2][4], aB[2][4];
    #pragma unroll
    for (int kt = 0; kt < 2; ++kt) {
        const int h0 = kt*32 + grp*8;
        const float4 a01 = *(const float4*)(&Ash[wid][h0]);
        const float4 a23 = *(const float4*)(&Ash[wid][h0+4]);
        const float4 b01 = *(const float4*)(&Bsh[wid][h0]);
        const float4 b23 = *(const float4*)(&Bsh[wid][h0+4]);
        aA[kt][0] = f32x2{a01.x, a01.y}; aA[kt][1] = f32x2{a01.z, a01.w};
        aA[kt][2] = f32x2{a23.x, a23.y}; aA[kt][3] = f32x2{a23.z, a23.w};
        aB[kt][0] = f32x2{b01.x, b01.y}; aB[kt][1] = f32x2{b01.z, b01.w};
        aB[kt][2] = f32x2{b23.x, b23.y}; aB[kt][3] = f32x2{b23.z, b23.w};
    }

    // B-fragment: two 16B reads of fp16 W2^T (zero for col>=4)
    half8 bfrag[2] = {};
    if (col < 4) {
        bfrag[0] = *(const half8*)(&W2T[wid][col][grp*8]);
        bfrag[1] = *(const half8*)(&W2T[wid][col][32 + grp*8]);
    }

    // sep from neighbor t (per-wave LDS, conflict-free)
    const float tn  = tsh[wid][(lane+1) & 63];
    const float sep = (lane < NUM_SAMPLES-1) ? (tn - t) : bin_dt;

    const fp16x2 hzero = {(__fp16)0.0f, (__fp16)0.0f};

    // 4 M-tiles of 16 samples; per tile: build A-frag (pk affine + pk relu) + 2 MFMA
    #pragma unroll
    for (int m = 0; m < 4; ++m) {
        const float tm = tsh[wid][col + 16*m];
        const f32x2 tv = {tm, tm};
        float4t c = {0.f, 0.f, 0.f, 0.f};
        #pragma unroll
        for (int kt = 0; kt < 2; ++kt) {
            union { fp16x2 h2[4]; half8 h8; } au;
            #pragma unroll
            for (int q = 0; q < 4; ++q) {
                const f32x2 pre = __builtin_elementwise_fma(aA[kt][q], tv, aB[kt][q]);
                const fp16x2 h = __builtin_amdgcn_cvt_pkrtz(pre.x, pre.y);
                au.h2[q] = __builtin_elementwise_max(h, hzero);
            }
            c = __builtin_amdgcn_mfma_f32_16x16x32_f16(au.h8, bfrag[kt], c, 0, 0, 0);
        }
        if (col < 4) {
            #pragma unroll
            for (int r = 0; r < 4; ++r) {
                const int sample = 16*m + grp*4 + r;
                cst[wid][sample*5 + col] = c[r];
            }
        }
    }

    // read back this lane's sample outputs (stride 5: conflict-free)
    const float acc0 = cst[wid][lane*5 + 0] + b2[0];
    const float acc1 = cst[wid][lane*5 + 1] + b2[1];
    const float acc2 = cst[wid][lane*5 + 2] + b2[2];
    const float acc3 = cst[wid][lane*5 + 3] + b2[3];

    // volume rendering composite, log2-space cumprod via DPP scan
    const float density = fmaxf(acc0, 0.0f);
    const float dsep  = density * sep;
    const float alpha = 1.0f - __expf(-dsep);
    const float lg    = -dsep * 1.44269504088896f;   // log2(1-alpha), exact
    const float S     = wave_scan_add(lg);           // inclusive cumsum
    const float T     = exp2f(S - lg);               // exclusive transmittance
    const float w     = alpha * T;

    float c0 = w * __builtin_amdgcn_rcpf(1.0f + __expf(-acc1));
    float c1 = w * __builtin_amdgcn_rcpf(1.0f + __expf(-acc2));
    float c2 = w * __builtin_amdgcn_rcpf(1.0f + __expf(-acc3));
    c0 = wave_scan_add(c0);                          // lane63 = total
    c1 = wave_scan_add(c1);
    c2 = wave_scan_add(c2);
    if (lane == 63) {
        out[ray*3+0] = c0;
        out[ray*3+1] = c1;
        out[ray*3+2] = c2;
    }
}

extern "C" void kernel_launch(void* const* d_in, const int* in_sizes, int n_in,
                              void* d_out, int out_size, void* d_ws, size_t ws_size,
                              hipStream_t stream) {
    const float* cam   = (const float*)d_in[0];
    const float* u     = (const float*)d_in[1];
    const float* cdirs = (const float*)d_in[2];
    const float* W1    = (const float*)d_in[3];
    const float* b1    = (const float*)d_in[4];
    const float* W2    = (const float*)d_in[5];
    const float* b2    = (const float*)d_in[6];
    float* out = (float*)d_out;

    const int R = 256 * 256;
    dim3 grid(R / 4), block(256);
    render_kernel<<<grid, block, 0, stream>>>(cam, u, cdirs, W1, b1, W2, b2, out);
}

// Round 6
// 30.298 us; speedup vs baseline: 1.3908x; 1.0960x over previous
//
#include <hip/hip_runtime.h>

#define NUM_SAMPLES 64
#define HIDDEN 64
#define Z_NEAR 2.0f
#define Z_FAR 6.0f

typedef _Float16 half8 __attribute__((ext_vector_type(8)));
typedef __fp16  fp16x2 __attribute__((ext_vector_type(2)));
typedef float   float4t __attribute__((ext_vector_type(4)));

// 6-step wave64 inclusive add-scan, pure VALU (DPP), zero LDS traffic.
template<int CTRL, int RMASK>
__device__ __forceinline__ float dpp_add(float x) {
    const int m = __builtin_amdgcn_update_dpp(0, __float_as_int(x), CTRL, RMASK, 0xf, true);
    return x + __int_as_float(m);
}
__device__ __forceinline__ float wave_scan_add(float x) {
    x = dpp_add<0x111, 0xf>(x);   // row_shr:1
    x = dpp_add<0x112, 0xf>(x);   // row_shr:2
    x = dpp_add<0x114, 0xf>(x);   // row_shr:4
    x = dpp_add<0x118, 0xf>(x);   // row_shr:8
    x = dpp_add<0x142, 0xa>(x);   // row_bcast:15 -> rows 1,3
    x = dpp_add<0x143, 0xc>(x);   // row_bcast:31 -> rows 2,3
    return x;                     // lane63 = full sum
}

// wave-per-ray, lane-per-sample; layer-1 affine-in-t factorization;
// coefficients stored fp16 in LDS, inner loop = v_pk_fma_f16 + v_pk_max_f16;
// layer-2 64->4 via mfma_f32_16x16x32_f16 (b2 folded into C init);
// composite via DPP log-space scan. Per-wave LDS only -> no barriers.
__global__ __launch_bounds__(256) void render_kernel(
    const float* __restrict__ cam,    // 4x4
    const float* __restrict__ u,      // R x S
    const float* __restrict__ cdirs,  // R x 3
    const float* __restrict__ W1,     // 6 x 64
    const float* __restrict__ b1,     // 64
    const float* __restrict__ W2,     // 64 x 4
    const float* __restrict__ b2,     // 4
    float* __restrict__ out)          // R x 3
{
    const int lane = threadIdx.x & 63;
    const int wid  = threadIdx.x >> 6;
    const int ray  = blockIdx.x * 4 + wid;
    const int grp  = lane >> 4;       // 16-lane group (k-group / C row group)
    const int col  = lane & 15;       // A row (sample-in-tile) / B,C col

    __shared__ __align__(16) __fp16 Ahsh[4][HIDDEN];
    __shared__ __align__(16) __fp16 Bhsh[4][HIDDEN];
    __shared__ __align__(16) float  tsh[4][NUM_SAMPLES];
    __shared__ __align__(16) __fp16 W2T[4][4][80];   // fp16 W2^T, padded rows
    __shared__ float cst[4][NUM_SAMPLES * 5];        // stride 5: conflict-free

    // per-wave fp16 W2^T staging (lane = hidden unit h)
    {
        const float4 w2row = ((const float4*)W2)[lane];
        W2T[wid][0][lane] = (__fp16)w2row.x;
        W2T[wid][1][lane] = (__fp16)w2row.y;
        W2T[wid][2][lane] = (__fp16)w2row.z;
        W2T[wid][3][lane] = (__fp16)w2row.w;
    }

    // ray dir / origin
    const float cd0 = cdirs[ray*3+0], cd1 = cdirs[ray*3+1], cd2 = cdirs[ray*3+2];
    const float rd0 = fmaf(cam[0], cd0, fmaf(cam[1], cd1, cam[2]*cd2));
    const float rd1 = fmaf(cam[4], cd0, fmaf(cam[5], cd1, cam[6]*cd2));
    const float rd2 = fmaf(cam[8], cd0, fmaf(cam[9], cd1, cam[10]*cd2));
    const float o0 = cam[3], o1 = cam[7], o2 = cam[11];

    // per-hidden-unit affine coeffs: pre_h(t) = A_h*t + B_h ; lane computes h=lane
    {
        const int h = lane;
        const float w10 = W1[0*HIDDEN+h], w11 = W1[1*HIDDEN+h], w12 = W1[2*HIDDEN+h];
        const float w13 = W1[3*HIDDEN+h], w14 = W1[4*HIDDEN+h], w15 = W1[5*HIDDEN+h];
        const float A = fmaf(rd0, w10, fmaf(rd1, w11, rd2*w12));
        float B = fmaf(o0, w10, fmaf(o1, w11, o2*w12));
        B = fmaf(rd0, w13, fmaf(rd1, w14, fmaf(rd2, w15, B))) + b1[h];
        Ahsh[wid][lane] = (__fp16)A;
        Bhsh[wid][lane] = (__fp16)B;
    }

    const float bin_dt = (Z_FAR - Z_NEAR) / (float)NUM_SAMPLES;
    const float uv = u[ray*NUM_SAMPLES + lane];             // coalesced
    const float t  = fmaf((float)lane + uv, bin_dt, Z_NEAR);
    tsh[wid][lane] = t;

    // hoisted fp16 coefficient pairs for this lane's k-slots: h = kt*32 + grp*8 + 2q
    union { fp16x2 h2[4]; half8 h8; } aAh[2], aBh[2];
    #pragma unroll
    for (int kt = 0; kt < 2; ++kt) {
        const int h0 = kt*32 + grp*8;
        aAh[kt].h8 = *(const half8*)(&Ahsh[wid][h0]);
        aBh[kt].h8 = *(const half8*)(&Bhsh[wid][h0]);
    }

    // B-fragment: two 16B reads of fp16 W2^T (zero for col>=4)
    half8 bfrag[2] = {};
    if (col < 4) {
        bfrag[0] = *(const half8*)(&W2T[wid][col][grp*8]);
        bfrag[1] = *(const half8*)(&W2T[wid][col][32 + grp*8]);
    }
    const float b2v = b2[col & 3];   // C-accumulator init (cols>=4 unused)

    // sep from neighbor t (per-wave LDS, conflict-free)
    const float tn  = tsh[wid][(lane+1) & 63];
    const float sep = (lane < NUM_SAMPLES-1) ? (tn - t) : bin_dt;

    const fp16x2 hzero = {(__fp16)0.0f, (__fp16)0.0f};

    // 4 M-tiles of 16 samples; per tile: A-frag (pk_fma_f16 + pk_max_f16) + 2 MFMA
    #pragma unroll
    for (int m = 0; m < 4; ++m) {
        const float tm = tsh[wid][col + 16*m];
        const fp16x2 tvh = __builtin_amdgcn_cvt_pkrtz(tm, tm);
        float4t c = {b2v, b2v, b2v, b2v};
        #pragma unroll
        for (int kt = 0; kt < 2; ++kt) {
            union { fp16x2 h2[4]; half8 h8; } au;
            #pragma unroll
            for (int q = 0; q < 4; ++q) {
                const fp16x2 pre = __builtin_elementwise_fma(aAh[kt].h2[q], tvh, aBh[kt].h2[q]);
                au.h2[q] = __builtin_elementwise_max(pre, hzero);
            }
            c = __builtin_amdgcn_mfma_f32_16x16x32_f16(au.h8, bfrag[kt], c, 0, 0, 0);
        }
        if (col < 4) {
            #pragma unroll
            for (int r = 0; r < 4; ++r) {
                const int sample = 16*m + grp*4 + r;
                cst[wid][sample*5 + col] = c[r];
            }
        }
    }

    // read back this lane's sample outputs (stride 5: conflict-free; b2 included)
    const float acc0 = cst[wid][lane*5 + 0];
    const float acc1 = cst[wid][lane*5 + 1];
    const float acc2 = cst[wid][lane*5 + 2];
    const float acc3 = cst[wid][lane*5 + 3];

    // volume rendering composite, log2-space cumprod via DPP scan
    const float density = fmaxf(acc0, 0.0f);
    const float dsep  = density * sep;
    const float alpha = 1.0f - __expf(-dsep);
    const float lg    = -dsep * 1.44269504088896f;   // log2(1-alpha), exact
    const float S     = wave_scan_add(lg);           // inclusive cumsum
    const float T     = exp2f(S - lg);               // exclusive transmittance
    const float w     = alpha * T;

    float c0 = w * __builtin_amdgcn_rcpf(1.0f + __expf(-acc1));
    float c1 = w * __builtin_amdgcn_rcpf(1.0f + __expf(-acc2));
    float c2 = w * __builtin_amdgcn_rcpf(1.0f + __expf(-acc3));
    c0 = wave_scan_add(c0);                          // lane63 = total
    c1 = wave_scan_add(c1);
    c2 = wave_scan_add(c2);
    if (lane == 63) {
        out[ray*3+0] = c0;
        out[ray*3+1] = c1;
        out[ray*3+2] = c2;
    }
}

extern "C" void kernel_launch(void* const* d_in, const int* in_sizes, int n_in,
                              void* d_out, int out_size, void* d_ws, size_t ws_size,
                              hipStream_t stream) {
    const float* cam   = (const float*)d_in[0];
    const float* u     = (const float*)d_in[1];
    const float* cdirs = (const float*)d_in[2];
    const float* W1    = (const float*)d_in[3];
    const float* b1    = (const float*)d_in[4];
    const float* W2    = (const float*)d_in[5];
    const float* b2    = (const float*)d_in[6];
    float* out = (float*)d_out;

    const int R = 256 * 256;
    dim3 grid(R / 4), block(256);
    render_kernel<<<grid, block, 0, stream>>>(cam, u, cdirs, W1, b1, W2, b2, out);
}